// Round 5
// baseline (525.344 us; speedup 1.0000x reference)
//
#include <hip/hip_runtime.h>
#include <hip/hip_bf16.h>

// HopfieldLayer: out = softmax(x @ Wl^T * beta) @ Wc^T
//   x [16384,768] f32, Wl [4096,768] f32, Wc [768,4096] f32 -> out [16384,768] f32
// R5: R3 structure (BK=32 double-buffered, prefetch-before-compute, 32KB LDS,
// 4 blocks/CU) but with 32x32x16 MFMA instead of 16x16x32: 18% fewer MFMA
// cycles/FLOP (2495 vs 2075 TF ubench), half the MFMA and ds_read instruction
// count, 4 long acc chains instead of 16 short ones.

#define NTOK   16384
#define DIM    768
#define NPROT  4096
#define BETA_F 0.03608439182428583f

typedef __bf16 bf16_t;
typedef __bf16 bf16x8 __attribute__((ext_vector_type(8)));
typedef float  floatx16 __attribute__((ext_vector_type(16)));

// ---------------------------------------------------------------- async 16B copy
__device__ __forceinline__ void async_copy16(const bf16_t* g, void* l) {
  __builtin_amdgcn_global_load_lds(
      (__attribute__((address_space(1))) const void*)g,
      (__attribute__((address_space(3))) void*)l, 16, 0, 0);
}

// ---------------------------------------------------------------- f32 -> bf16 (all 3 inputs)
__global__ __launch_bounds__(256) void cvt_all(
    const float* __restrict__ x, const float* __restrict__ wl,
    const float* __restrict__ wc, bf16_t* __restrict__ xb,
    bf16_t* __restrict__ wlb, bf16_t* __restrict__ wcb,
    int nx8, int nw8, int nc8) {
  int i = blockIdx.x * 256 + threadIdx.x;
  const float* in; bf16_t* out; int k;
  if (i < nx8)            { in = x;  out = xb;  k = i; }
  else if (i < nx8 + nw8) { in = wl; out = wlb; k = i - nx8; }
  else if (i < nx8 + nw8 + nc8) { in = wc; out = wcb; k = i - nx8 - nw8; }
  else return;
  const float4* in4 = (const float4*)in;
  float4 a = in4[2 * k], b = in4[2 * k + 1];
  bf16x8 o;
  o[0] = (bf16_t)a.x; o[1] = (bf16_t)a.y; o[2] = (bf16_t)a.z; o[3] = (bf16_t)a.w;
  o[4] = (bf16_t)b.x; o[5] = (bf16_t)b.y; o[6] = (bf16_t)b.z; o[7] = (bf16_t)b.w;
  ((bf16x8*)out)[k] = o;
}

// ---------------------------------------------------------------- gemm C = A * B^T
// A: M x K row-major bf16, B: N x K row-major bf16. 128x128 tile, 4 waves 2x2,
// each 64x64 = 2x2 tiles of 32x32x16 MFMA. BK=32 double-buffered (halves at
// bytes 0 / 16384; each half: A frags 8KB + B frags 8KB).
// Fragment = 32 rows x 16 k = 1KB; lane slot l holds row (l&31),
// k ((l>>5)*8..+7) -> matches global_load_lds uniform-base+lane*16 AND
// conflict-free ds_read_b128. Frag id for (rowgrp fm, kstep fk) = fm*2+fk.
// A-operand layout 32x32x16: A[row=l&31][k=(l>>5)*8+j]; C/D layout (m74/m101):
// col = lane&31, row = (reg&3) + 8*(reg>>2) + 4*(lane>>5).
// EPI 0: P = exp(beta*acc) bf16 + shuffle rowsum + atomicAdd.  EPI 1: acc/rowsum.
template <int EPI>
__global__ __launch_bounds__(256, 4)
void gemm_bt(const bf16_t* __restrict__ A, const bf16_t* __restrict__ B,
             void* __restrict__ Cv, float* __restrict__ rowsum,
             const int K, const int N) {
  __shared__ alignas(16) char lds[32768];

  const int tid = threadIdx.x;
  const int l   = tid & 63;
  const int w   = tid >> 6;
  const int wr  = w >> 1;        // wave row (0..1)
  const int wc  = w & 1;         // wave col (0..1)
  const int lr  = l & 31;        // row within 32-row fragment
  const int lk  = (l >> 5) << 3; // k offset within fragment (0 or 8)
  const int m0  = blockIdx.x * 128;
  const int n0  = blockIdx.y * 128;

  // staging: thread (w,l), chunk j -> fragment j*4+w (fm = f>>1, fk = f&1)
  int abase[2], bbase[2];
#pragma unroll
  for (int j = 0; j < 2; ++j) {
    const int f  = j * 4 + w;
    const int fm = f >> 1, fk = f & 1;
    abase[j] = (m0 + fm * 32 + lr) * K + fk * 16 + lk;
    bbase[j] = (n0 + fm * 32 + lr) * K + fk * 16 + lk;
  }

  auto stage = [&](char* buf, int k0) {
    bf16x8* Af = (bf16x8*)buf;
    bf16x8* Bf = (bf16x8*)(buf + 8192);
#pragma unroll
    for (int j = 0; j < 2; ++j) {
      const int f = j * 4 + w;
      async_copy16(A + abase[j] + k0, Af + f * 64);
      async_copy16(B + bbase[j] + k0, Bf + f * 64);
    }
  };

  floatx16 acc[2][2];
#pragma unroll
  for (int mt = 0; mt < 2; ++mt)
#pragma unroll
    for (int nt = 0; nt < 2; ++nt)
#pragma unroll
      for (int r = 0; r < 16; ++r) acc[mt][nt][r] = 0.f;

  auto compute = [&](const char* buf) {
    const bf16x8* Af = (const bf16x8*)buf;
    const bf16x8* Bf = (const bf16x8*)(buf + 8192);
#pragma unroll
    for (int kt = 0; kt < 2; ++kt) {
      bf16x8 af[2], bg[2];
#pragma unroll
      for (int mt = 0; mt < 2; ++mt) af[mt] = Af[((wr * 2 + mt) * 2 + kt) * 64 + l];
#pragma unroll
      for (int nt = 0; nt < 2; ++nt) bg[nt] = Bf[((wc * 2 + nt) * 2 + kt) * 64 + l];
#pragma unroll
      for (int mt = 0; mt < 2; ++mt)
#pragma unroll
        for (int nt = 0; nt < 2; ++nt)
          acc[mt][nt] = __builtin_amdgcn_mfma_f32_32x32x16_bf16(af[mt], bg[nt],
                                                                acc[mt][nt], 0, 0, 0);
    }
  };

  const int iters = K >> 5;  // 24 (K=768) or 128 (K=4096) -- both even
  stage(lds, 0);
  __syncthreads();
  for (int it = 0; it < iters; it += 2) {
    stage(lds + 16384, (it + 1) << 5);   // prefetch odd tile, flies during compute
    compute(lds);
    __syncthreads();
    if (it + 2 < iters) stage(lds, (it + 2) << 5);
    compute(lds + 16384);
    __syncthreads();
  }

  // C/D layout: col = lane&31, row = (reg&3) + 8*(reg>>2) + 4*(lane>>5)
  const int rowb = m0 + wr * 64;
  const int colb = n0 + wc * 64;
  const int rhalf = (l >> 5) << 2;  // +4 for lanes 32..63
  if (EPI == 0) {
    bf16_t* P = (bf16_t*)Cv;
#pragma unroll
    for (int mt = 0; mt < 2; ++mt) {
      float rsum[16];
#pragma unroll
      for (int r = 0; r < 16; ++r) rsum[r] = 0.f;
#pragma unroll
      for (int nt = 0; nt < 2; ++nt) {
        const int col = colb + nt * 32 + lr;
#pragma unroll
        for (int r = 0; r < 16; ++r) {
          const float e = __expf(acc[mt][nt][r] * BETA_F);
          const int row = rowb + mt * 32 + (r & 3) + 8 * (r >> 2) + rhalf;
          P[row * N + col] = (bf16_t)e;
          rsum[r] += e;
        }
      }
#pragma unroll
      for (int r = 0; r < 16; ++r) {  // reduce across the 32 col-lanes (bits 0..4)
        float s = rsum[r];
        s += __shfl_xor(s, 1);
        s += __shfl_xor(s, 2);
        s += __shfl_xor(s, 4);
        s += __shfl_xor(s, 8);
        s += __shfl_xor(s, 16);
        if (lr == 0)
          atomicAdd(&rowsum[rowb + mt * 32 + (r & 3) + 8 * (r >> 2) + rhalf], s);
      }
    }
  } else {
    float* O = (float*)Cv;
#pragma unroll
    for (int mt = 0; mt < 2; ++mt) {
#pragma unroll
      for (int r = 0; r < 16; ++r) {
        const int row = rowb + mt * 32 + (r & 3) + 8 * (r >> 2) + rhalf;
        const float inv = 1.0f / rowsum[row];
#pragma unroll
        for (int nt = 0; nt < 2; ++nt)
          O[row * N + colb + nt * 32 + lr] = acc[mt][nt][r] * inv;
      }
    }
  }
}

// ---------------------------------------------------------------- fallback (no ws)
__global__ __launch_bounds__(256) void hopfield_fallback(
    const float* __restrict__ x, const float* __restrict__ wl,
    const float* __restrict__ wc, float* __restrict__ out) {
  __shared__ float  xs[8 * 768];
  __shared__ bf16_t ps[8 * 4096];
  __shared__ float  rs[8];
  const int tid = threadIdx.x;
  const int r0  = blockIdx.x * 8;
  if (tid < 8) rs[tid] = 0.f;
  for (int i = tid; i < 8 * 768; i += 256)
    xs[i] = x[(r0 + (i / 768)) * 768 + (i % 768)];
  __syncthreads();

  float lsum[8] = {0, 0, 0, 0, 0, 0, 0, 0};
  for (int p = tid; p < 4096; p += 256) {
    float s[8] = {0, 0, 0, 0, 0, 0, 0, 0};
    for (int d = 0; d < 768; ++d) {
      const float wv = wl[p * 768 + d];
#pragma unroll
      for (int r = 0; r < 8; ++r) s[r] += xs[r * 768 + d] * wv;
    }
#pragma unroll
    for (int r = 0; r < 8; ++r) {
      const float e = __expf(s[r] * BETA_F);
      ps[r * 4096 + p] = (bf16_t)e;
      lsum[r] += e;
    }
  }
#pragma unroll
  for (int r = 0; r < 8; ++r) atomicAdd(&rs[r], lsum[r]);
  __syncthreads();

  for (int d = tid; d < 768; d += 256) {
    float o[8] = {0, 0, 0, 0, 0, 0, 0, 0};
    for (int p = 0; p < 4096; ++p) {
      const float wv = wc[d * 4096 + p];
#pragma unroll
      for (int r = 0; r < 8; ++r) o[r] += (float)ps[r * 4096 + p] * wv;
    }
#pragma unroll
    for (int r = 0; r < 8; ++r) out[(r0 + r) * 768 + d] = o[r] / rs[r];
  }
}

// ---------------------------------------------------------------- launcher
extern "C" void kernel_launch(void* const* d_in, const int* in_sizes, int n_in,
                              void* d_out, int out_size, void* d_ws, size_t ws_size,
                              hipStream_t stream) {
  (void)in_sizes; (void)n_in; (void)out_size;
  const float* x  = (const float*)d_in[0];
  const float* wl = (const float*)d_in[1];
  const float* wc = (const float*)d_in[2];
  float* out = (float*)d_out;

  const size_t xb_e = (size_t)NTOK * DIM;
  const size_t wl_e = (size_t)NPROT * DIM;
  const size_t wc_e = (size_t)DIM * NPROT;
  const size_t P_e  = (size_t)NTOK * NPROT;
  const size_t need = (xb_e + wl_e + wc_e + P_e) * 2 + (size_t)NTOK * 4;

  if (ws_size >= need) {
    char* ws = (char*)d_ws;
    bf16_t* xb  = (bf16_t*)ws;  ws += xb_e * 2;
    bf16_t* wlb = (bf16_t*)ws;  ws += wl_e * 2;
    bf16_t* wcb = (bf16_t*)ws;  ws += wc_e * 2;
    bf16_t* P   = (bf16_t*)ws;  ws += P_e * 2;
    float* rowsum = (float*)ws;

    hipMemsetAsync(rowsum, 0, NTOK * sizeof(float), stream);
    const int nx8 = (int)(xb_e / 8), nw8 = (int)(wl_e / 8), nc8 = (int)(wc_e / 8);
    cvt_all<<<(nx8 + nw8 + nc8 + 255) / 256, 256, 0, stream>>>(
        x, wl, wc, xb, wlb, wcb, nx8, nw8, nc8);
    // scores+exp+rowsum: M=16384, N=4096, K=768
    gemm_bt<0><<<dim3(NTOK / 128, NPROT / 128), 256, 0, stream>>>(
        xb, wlb, (void*)P, rowsum, DIM, NPROT);
    // content+normalize: M=16384, N=768, K=4096
    gemm_bt<1><<<dim3(NTOK / 128, DIM / 128), 256, 0, stream>>>(
        P, wcb, (void*)out, rowsum, NPROT, DIM);
  } else {
    hopfield_fallback<<<NTOK / 8, 256, 0, stream>>>(x, wl, wc, out);
  }
}

// Round 6
// 497.430 us; speedup vs baseline: 1.0561x; 1.0561x over previous
//
#include <hip/hip_runtime.h>
#include <hip/hip_bf16.h>

// HopfieldLayer: out = softmax(x @ Wl^T * beta) @ Wc^T
//   x [16384,768] f32, Wl [4096,768] f32, Wc [768,4096] f32 -> out [16384,768] f32
// R6: GEMM1 -> MX-fp8 (mfma_scale 16x16x128, constant scale=1.0, Wl pre-scaled
// x64; m148 measured 1628 TF for this family vs 874 bf16). GEMM2 stays bf16
// (P~1.0 in e4m3 would give ~5e-5 output error > 1.9e-5 threshold).

#define NTOK   16384
#define DIM    768
#define NPROT  4096
#define BETA_F 0.03608439182428583f

typedef __bf16 bf16_t;
typedef __bf16 bf16x8 __attribute__((ext_vector_type(8)));
typedef float  floatx4 __attribute__((ext_vector_type(4)));
typedef int    intx4  __attribute__((ext_vector_type(4)));
typedef int    intx8  __attribute__((ext_vector_type(8)));

// ---------------------------------------------------------------- async 16B copy
__device__ __forceinline__ void async_copy16(const void* g, void* l) {
  __builtin_amdgcn_global_load_lds(
      (__attribute__((address_space(1))) const void*)g,
      (__attribute__((address_space(3))) void*)l, 16, 0, 0);
}

// ---------------------------------------------------------------- convert inputs
// x -> fp8 e4m3 (scale 1), wl -> fp8 e4m3 (x64), wc -> bf16
__global__ __launch_bounds__(256) void cvt_all(
    const float* __restrict__ x, const float* __restrict__ wl,
    const float* __restrict__ wc, unsigned char* __restrict__ x8,
    unsigned char* __restrict__ wl8, bf16_t* __restrict__ wcb,
    int nx8, int nw8, int nc8) {
  int i = blockIdx.x * 256 + threadIdx.x;
  if (i < nx8 + nw8) {  // fp8 targets
    const float* in; unsigned char* out; float sc; int k;
    if (i < nx8) { in = x;  out = x8;  sc = 1.0f;  k = i; }
    else         { in = wl; out = wl8; sc = 64.0f; k = i - nx8; }
    const float4* in4 = (const float4*)in;
    float4 a = in4[2 * k], b = in4[2 * k + 1];
    int d0 = __builtin_amdgcn_cvt_pk_fp8_f32(a.x * sc, a.y * sc, 0, false);
    d0 = __builtin_amdgcn_cvt_pk_fp8_f32(a.z * sc, a.w * sc, d0, true);
    int d1 = __builtin_amdgcn_cvt_pk_fp8_f32(b.x * sc, b.y * sc, 0, false);
    d1 = __builtin_amdgcn_cvt_pk_fp8_f32(b.z * sc, b.w * sc, d1, true);
    ((int2*)out)[k] = make_int2(d0, d1);
  } else if (i < nx8 + nw8 + nc8) {
    int k = i - nx8 - nw8;
    const float4* in4 = (const float4*)wc;
    float4 a = in4[2 * k], b = in4[2 * k + 1];
    bf16x8 o;
    o[0] = (bf16_t)a.x; o[1] = (bf16_t)a.y; o[2] = (bf16_t)a.z; o[3] = (bf16_t)a.w;
    o[4] = (bf16_t)b.x; o[5] = (bf16_t)b.y; o[6] = (bf16_t)b.z; o[7] = (bf16_t)b.w;
    ((bf16x8*)wcb)[k] = o;
  }
}

// ---------------------------------------------------------------- GEMM1 (fp8 MX)
// P = exp(beta * (x @ Wl^T)) bf16 + rowsum.  A8: 16384x768 fp8, B8: 4096x768
// fp8 (x64). 128x128 tile, 4 waves 2x2 (each 64x64 = 4x4 of 16x16x128 MFMA),
// BK=128 (one MFMA K-step), double-buffered 2x32KB.
// Fragment (16 rows x 128 k = 2KB fp8) = two 1KB glds sub-blocks: sub h holds
// lane l's bytes row (l&15), k (l>>4)*32 + h*16 .. +15  -> register v[0:3]=k
// lo, v[4:7]=k hi gives the 32-consecutive-k A-operand of 16x16x128.
__global__ __launch_bounds__(256)
void gemm1_fp8(const unsigned char* __restrict__ A8,
               const unsigned char* __restrict__ B8,
               bf16_t* __restrict__ P, float* __restrict__ rowsum) {
  constexpr int K = DIM;    // 768 (bytes per row in fp8)
  constexpr int N = NPROT;  // 4096
  __shared__ alignas(16) char lds[2][32768];  // per stage: A 16KB @0, B 16KB @16384

  const int tid = threadIdx.x;
  const int l   = tid & 63;
  const int w   = tid >> 6;
  const int wr  = w >> 1;
  const int wc  = w & 1;
  const int lr  = l & 15;
  const int lk  = (l >> 4) << 5;      // 0,32,64,96
  const int n0  = blockIdx.x * 128;   // n fastest: 32 blocks share an A-band
  const int m0  = blockIdx.y * 128;

  // 32 glds sub-blocks per stage (A:0..15, B:16..31); wave w takes id = j*4+w
  const unsigned char* sptr[8];
  int goff[8], loff[8];
#pragma unroll
  for (int j = 0; j < 8; ++j) {
    const int id = j * 4 + w;
    const int f = (id >> 1) & 7, h = id & 1;
    const bool isB = id >= 16;
    sptr[j] = isB ? B8 : A8;
    goff[j] = ((isB ? n0 : m0) + f * 16 + lr) * K + lk + h * 16;
    loff[j] = (isB ? 16384 : 0) + f * 2048 + h * 1024;  // wave-uniform LDS base
  }

  auto stage = [&](int s, int k0) {
#pragma unroll
    for (int j = 0; j < 8; ++j)
      async_copy16(sptr[j] + goff[j] + k0, lds[s] + loff[j]);
  };

  const floatx4 z = {0.f, 0.f, 0.f, 0.f};
  floatx4 acc[4][4];
#pragma unroll
  for (int mt = 0; mt < 4; ++mt)
#pragma unroll
    for (int nt = 0; nt < 4; ++nt) acc[mt][nt] = z;

  auto compute = [&](int s) {
    const char* buf = lds[s];
    intx8 av[4], bv[4];
#pragma unroll
    for (int mt = 0; mt < 4; ++mt) {
      const int f = wr * 4 + mt;
      intx4 lo = *(const intx4*)(buf + f * 2048 + l * 16);
      intx4 hi = *(const intx4*)(buf + f * 2048 + 1024 + l * 16);
      intx8 v; v[0]=lo[0]; v[1]=lo[1]; v[2]=lo[2]; v[3]=lo[3];
               v[4]=hi[0]; v[5]=hi[1]; v[6]=hi[2]; v[7]=hi[3];
      av[mt] = v;
    }
#pragma unroll
    for (int nt = 0; nt < 4; ++nt) {
      const int f = wc * 4 + nt;
      intx4 lo = *(const intx4*)(buf + 16384 + f * 2048 + l * 16);
      intx4 hi = *(const intx4*)(buf + 16384 + f * 2048 + 1024 + l * 16);
      intx8 v; v[0]=lo[0]; v[1]=lo[1]; v[2]=lo[2]; v[3]=lo[3];
               v[4]=hi[0]; v[5]=hi[1]; v[6]=hi[2]; v[7]=hi[3];
      bv[nt] = v;
    }
#pragma unroll
    for (int mt = 0; mt < 4; ++mt)
#pragma unroll
      for (int nt = 0; nt < 4; ++nt)
        acc[mt][nt] = __builtin_amdgcn_mfma_scale_f32_16x16x128_f8f6f4(
            av[mt], bv[nt], acc[mt][nt], 0, 0, 0, 127, 0, 127);  // fmt fp8, scale 2^0
  };

  // K=768 -> 6 iterations of BK=128
  stage(0, 0);
  __syncthreads();
  for (int it = 0; it < 6; it += 2) {
    stage(1, (it + 1) << 7);
    compute(0);
    __syncthreads();
    if (it + 2 < 6) stage(0, (it + 2) << 7);
    compute(1);
    __syncthreads();
  }

  // C/D layout (shape-determined, = 16x16 bf16): col = lane&15, row = (l>>4)*4+i
  const int rowb = m0 + wr * 64;
  const int colb = n0 + wc * 64;
  constexpr float SC = BETA_F / 64.0f;  // undo Wl x64
#pragma unroll
  for (int mt = 0; mt < 4; ++mt) {
    float rsum[4] = {0.f, 0.f, 0.f, 0.f};
#pragma unroll
    for (int nt = 0; nt < 4; ++nt) {
#pragma unroll
      for (int i = 0; i < 4; ++i) {
        const float e = __expf(acc[mt][nt][i] * SC);
        const int row = rowb + mt * 16 + (l >> 4) * 4 + i;
        const int col = colb + nt * 16 + lr;
        P[row * N + col] = (bf16_t)e;
        rsum[i] += e;
      }
    }
#pragma unroll
    for (int i = 0; i < 4; ++i) {
      float s = rsum[i];
      s += __shfl_xor(s, 1);
      s += __shfl_xor(s, 2);
      s += __shfl_xor(s, 4);
      s += __shfl_xor(s, 8);
      if (lr == 0)
        atomicAdd(&rowsum[rowb + mt * 16 + (l >> 4) * 4 + i], s);
    }
  }
}

// ---------------------------------------------------------------- GEMM2 (bf16)
// out = (P @ Wc^T) / rowsum.  A: P 16384x4096 bf16, B: wcb 768x4096 bf16.
// R3 structure: 128x128 tile, 16x16x32 MFMA, BK=32 dbuf, fragment-ordered LDS.
__global__ __launch_bounds__(256, 4)
void gemm2_bf16(const bf16_t* __restrict__ A, const bf16_t* __restrict__ B,
                float* __restrict__ O, const float* __restrict__ rowsum) {
  constexpr int K = NPROT;  // 4096
  constexpr int N = DIM;    // 768
  __shared__ alignas(16) char lds[32768];

  const int tid = threadIdx.x;
  const int l   = tid & 63;
  const int w   = tid >> 6;
  const int wr  = w >> 1;
  const int wc  = w & 1;
  const int lr  = l & 15;
  const int lk  = (l >> 4) << 3;
  const int n0  = blockIdx.x * 128;   // n fastest: 6 blocks share an A-band
  const int m0  = blockIdx.y * 128;

  int abase[2], bbase[2];
#pragma unroll
  for (int j = 0; j < 2; ++j) {
    const int frag = j * 4 + w;
    abase[j] = (m0 + frag * 16 + lr) * K + lk;
    bbase[j] = (n0 + frag * 16 + lr) * K + lk;
  }

  auto stage = [&](char* buf, int k0) {
    bf16x8* Af = (bf16x8*)buf;
    bf16x8* Bf = (bf16x8*)(buf + 8192);
#pragma unroll
    for (int j = 0; j < 2; ++j) {
      const int frag = j * 4 + w;
      async_copy16(A + abase[j] + k0, Af + frag * 64);
      async_copy16(B + bbase[j] + k0, Bf + frag * 64);
    }
  };

  const floatx4 z = {0.f, 0.f, 0.f, 0.f};
  floatx4 acc[4][4];
#pragma unroll
  for (int mt = 0; mt < 4; ++mt)
#pragma unroll
    for (int nt = 0; nt < 4; ++nt) acc[mt][nt] = z;

  auto compute = [&](const char* buf) {
    const bf16x8* Af = (const bf16x8*)buf;
    const bf16x8* Bf = (const bf16x8*)(buf + 8192);
    bf16x8 af[4], bg[4];
#pragma unroll
    for (int mt = 0; mt < 4; ++mt) af[mt] = Af[(wr * 4 + mt) * 64 + l];
#pragma unroll
    for (int nt = 0; nt < 4; ++nt) bg[nt] = Bf[(wc * 4 + nt) * 64 + l];
#pragma unroll
    for (int mt = 0; mt < 4; ++mt)
#pragma unroll
      for (int nt = 0; nt < 4; ++nt)
        acc[mt][nt] = __builtin_amdgcn_mfma_f32_16x16x32_bf16(af[mt], bg[nt],
                                                              acc[mt][nt], 0, 0, 0);
  };

  const int iters = K >> 5;  // 128
  stage(lds, 0);
  __syncthreads();
  for (int it = 0; it < iters; it += 2) {
    stage(lds + 16384, (it + 1) << 5);
    compute(lds);
    __syncthreads();
    if (it + 2 < iters) stage(lds, (it + 2) << 5);
    compute(lds + 16384);
    __syncthreads();
  }

  const int rowb = m0 + wr * 64;
  const int colb = n0 + wc * 64;
#pragma unroll
  for (int mt = 0; mt < 4; ++mt) {
#pragma unroll
    for (int i = 0; i < 4; ++i) {
      const int row = rowb + mt * 16 + (l >> 4) * 4 + i;
      const float inv = 1.0f / rowsum[row];
#pragma unroll
      for (int nt = 0; nt < 4; ++nt)
        O[row * N + colb + nt * 16 + lr] = acc[mt][nt][i] * inv;
    }
  }
}

// ---------------------------------------------------------------- fallback (no ws)
__global__ __launch_bounds__(256) void hopfield_fallback(
    const float* __restrict__ x, const float* __restrict__ wl,
    const float* __restrict__ wc, float* __restrict__ out) {
  __shared__ float  xs[8 * 768];
  __shared__ bf16_t ps[8 * 4096];
  __shared__ float  rs[8];
  const int tid = threadIdx.x;
  const int r0  = blockIdx.x * 8;
  if (tid < 8) rs[tid] = 0.f;
  for (int i = tid; i < 8 * 768; i += 256)
    xs[i] = x[(r0 + (i / 768)) * 768 + (i % 768)];
  __syncthreads();

  float lsum[8] = {0, 0, 0, 0, 0, 0, 0, 0};
  for (int p = tid; p < 4096; p += 256) {
    float s[8] = {0, 0, 0, 0, 0, 0, 0, 0};
    for (int d = 0; d < 768; ++d) {
      const float wv = wl[p * 768 + d];
#pragma unroll
      for (int r = 0; r < 8; ++r) s[r] += xs[r * 768 + d] * wv;
    }
#pragma unroll
    for (int r = 0; r < 8; ++r) {
      const float e = __expf(s[r] * BETA_F);
      ps[r * 4096 + p] = (bf16_t)e;
      lsum[r] += e;
    }
  }
#pragma unroll
  for (int r = 0; r < 8; ++r) atomicAdd(&rs[r], lsum[r]);
  __syncthreads();

  for (int d = tid; d < 768; d += 256) {
    float o[8] = {0, 0, 0, 0, 0, 0, 0, 0};
    for (int p = 0; p < 4096; ++p) {
      const float wv = wc[d * 4096 + p];
#pragma unroll
      for (int r = 0; r < 8; ++r) o[r] += (float)ps[r * 4096 + p] * wv;
    }
#pragma unroll
    for (int r = 0; r < 8; ++r) out[(r0 + r) * 768 + d] = o[r] / rs[r];
  }
}

// ---------------------------------------------------------------- launcher
extern "C" void kernel_launch(void* const* d_in, const int* in_sizes, int n_in,
                              void* d_out, int out_size, void* d_ws, size_t ws_size,
                              hipStream_t stream) {
  (void)in_sizes; (void)n_in; (void)out_size;
  const float* x  = (const float*)d_in[0];
  const float* wl = (const float*)d_in[1];
  const float* wc = (const float*)d_in[2];
  float* out = (float*)d_out;

  const size_t xb_e = (size_t)NTOK * DIM;    // 12.58M
  const size_t wl_e = (size_t)NPROT * DIM;   // 3.15M
  const size_t wc_e = (size_t)DIM * NPROT;   // 3.15M
  const size_t P_e  = (size_t)NTOK * NPROT;  // 67.1M
  const size_t need = xb_e + wl_e + wc_e * 2 + P_e * 2 + (size_t)NTOK * 4;

  if (ws_size >= need) {
    char* ws = (char*)d_ws;
    unsigned char* x8  = (unsigned char*)ws;  ws += xb_e;
    unsigned char* wl8 = (unsigned char*)ws;  ws += wl_e;
    bf16_t* wcb = (bf16_t*)ws;  ws += wc_e * 2;
    bf16_t* P   = (bf16_t*)ws;  ws += P_e * 2;
    float* rowsum = (float*)ws;

    hipMemsetAsync(rowsum, 0, NTOK * sizeof(float), stream);
    const int nx8 = (int)(xb_e / 8), nw8 = (int)(wl_e / 8), nc8 = (int)(wc_e / 8);
    cvt_all<<<(nx8 + nw8 + nc8 + 255) / 256, 256, 0, stream>>>(
        x, wl, wc, x8, wl8, wcb, nx8, nw8, nc8);
    gemm1_fp8<<<dim3(NPROT / 128, NTOK / 128), 256, 0, stream>>>(x8, wl8, P, rowsum);
    gemm2_bf16<<<dim3(DIM / 128, NTOK / 128), 256, 0, stream>>>(P, wcb, out, rowsum);
  } else {
    hopfield_fallback<<<NTOK / 8, 256, 0, stream>>>(x, wl, wc, out);
  }
}